// Round 6
// baseline (1200.840 us; speedup 1.0000x reference)
//
#include <hip/hip_runtime.h>
#include <hip/hip_bf16.h>
#include <stdint.h>

#define L_DIM 2048
#define B_DIM 8
#define D_DIM 1024
#define M_DIM (L_DIM * B_DIM)   // 16384 rows
#define N_DIM (3 * D_DIM)       // 3072
#define K_DIM D_DIM             // 1024
#define CH    (B_DIM * D_DIM)   // 8192 scan channels
#define EPSLN 1e-5f
#define NC 128                  // scan chunks
#define CL (L_DIM / NC)         // 16 steps per chunk

// ---- GEMM geometry: 256^2 tile, BK=32, 64KB LDS -> 2 blocks/CU ----
#define BM 256
#define BN 256
#define BK 32
#define NT (K_DIM / BK)         // 32 K-tiles
#define GX (N_DIM / BN)         // 12
#define GY (M_DIM / BM)         // 64
#define NWG (GX * GY)           // 768 (divisible by 8 -> bijective XCD swizzle)

typedef __attribute__((ext_vector_type(8))) short short8;
typedef __attribute__((ext_vector_type(4))) float floatx4;

static __device__ __forceinline__ float bf16_lo(unsigned int p) {
    union { unsigned int u; float f; } v; v.u = p << 16; return v.f;
}
static __device__ __forceinline__ float bf16_hi(unsigned int p) {
    union { unsigned int u; float f; } v; v.u = p & 0xffff0000u; return v.f;
}
static __device__ __forceinline__ unsigned short f32_to_bf16(float f) {
    union { float f; unsigned int u; } v;
    v.f = f;
    unsigned int u = v.u;
    u += 0x7fffu + ((u >> 16) & 1u);   // round-to-nearest-even
    return (unsigned short)(u >> 16);
}
static __device__ __forceinline__ float sigmoidf_fast(float v) {
    return 1.0f / (1.0f + __expf(-v));
}
static __device__ __forceinline__ float tanhf_fast(float c) {
    return 1.0f - 2.0f / (1.0f + __expf(2.0f * c));
}

// async global -> LDS, 16B per lane (global_load_lds_dwordx4)
static __device__ __forceinline__ void async16(const void* g, void* l) {
    __builtin_amdgcn_global_load_lds(
        (const __attribute__((address_space(1))) unsigned int*)g,
        (__attribute__((address_space(3))) unsigned int*)l,
        16, 0, 0);
}

// ---------------- LayerNorm: x[M,D] fp32 -> x_norm bf16 [M,D] + mean/rstd ----
// wave-per-row (4 rows/block). No LDS, no __syncthreads. (r5, verified)
__global__ __launch_bounds__(256) void ln_kernel(const float* __restrict__ x,
                                                 const float* __restrict__ gamma,
                                                 const float* __restrict__ beta,
                                                 unsigned short* __restrict__ xn,
                                                 float* __restrict__ meanOut,
                                                 float* __restrict__ rstdOut) {
    const int wid  = threadIdx.x >> 6;          // wave 0..3
    const int lane = threadIdx.x & 63;
    const int row  = blockIdx.x * 4 + wid;
    const float* xr = x + (size_t)row * D_DIM;
    float4 v[4];
    float s = 0.0f, s2 = 0.0f;
    #pragma unroll
    for (int j = 0; j < 4; j++) {
        v[j] = *(const float4*)(xr + j * 256 + lane * 4);
        s  += v[j].x + v[j].y + v[j].z + v[j].w;
        s2 += v[j].x * v[j].x + v[j].y * v[j].y + v[j].z * v[j].z + v[j].w * v[j].w;
    }
    #pragma unroll
    for (int o = 32; o > 0; o >>= 1) {
        s  += __shfl_xor(s, o, 64);
        s2 += __shfl_xor(s2, o, 64);
    }
    const float mean = s * (1.0f / D_DIM);
    const float var  = s2 * (1.0f / D_DIM) - mean * mean;
    const float rstd = rsqrtf(var + EPSLN);
    if (lane == 0) { meanOut[row] = mean; rstdOut[row] = rstd; }
    #pragma unroll
    for (int j = 0; j < 4; j++) {
        const int col = j * 256 + lane * 4;
        const float4 g = *(const float4*)(gamma + col);
        const float4 b = *(const float4*)(beta + col);
        unsigned short o0 = f32_to_bf16((v[j].x - mean) * rstd * g.x + b.x);
        unsigned short o1 = f32_to_bf16((v[j].y - mean) * rstd * g.y + b.y);
        unsigned short o2 = f32_to_bf16((v[j].z - mean) * rstd * g.z + b.z);
        unsigned short o3 = f32_to_bf16((v[j].w - mean) * rstd * g.w + b.w);
        uint2 packed;
        packed.x = (unsigned int)o0 | ((unsigned int)o1 << 16);
        packed.y = (unsigned int)o2 | ((unsigned int)o3 << 16);
        *(uint2*)(xn + (size_t)row * D_DIM + col) = packed;
    }
}

// ---------------- W fp32 [3D, D] -> bf16 ----------------
__global__ __launch_bounds__(256) void wconv_kernel(const float* __restrict__ W,
                                                    unsigned short* __restrict__ Wb) {
    const size_t i = ((size_t)blockIdx.x * 256 + threadIdx.x) * 4;
    float4 v = *(const float4*)(W + i);
    uint2 packed;
    packed.x = (unsigned int)f32_to_bf16(v.x) | ((unsigned int)f32_to_bf16(v.y) << 16);
    packed.y = (unsigned int)f32_to_bf16(v.z) | ((unsigned int)f32_to_bf16(v.w) << 16);
    *(uint2*)(Wb + i) = packed;
}

// ---------------- GEMM: ufr[m,e] = sum_k xn[m,k] * W[e,k]  (NT, bf16 MFMA) ---
// ROUND-6: same octet operand-residency dataflow as r4, but BK=32 -> 64 KB
// LDS -> TWO blocks/CU (16 waves/CU, 4/SIMD via __launch_bounds__(512,4)).
// Rationale: rounds 1-5 all show MFMA-busy time == 43us (dur x MfmaUtil
// constant); everything else is stall, and at 1 block/CU there is nothing to
// hide stalls under. Cross-block overlap (m114/m97 mechanism) is runtime HW
// behavior -> robust to the codegen perturbation that flipped r4<->r5.
// Per K-tile (32 tiles): 4 octets x 8 MFMA; ONE vmcnt(0)+s_barrier+
// sched_barrier(0) after octet 3 (staging ~3 octets old); next-tile operand
// prefetch (aP/b0) reads after the barrier, consumed next tile's O1/O2.
// Register roles (static indices): aP: A-h0 -> A-h0'(prefetch); aQ: A-h1;
// b0: B-h0 -> B-h0'(prefetch); b1: B-h1. Frags = 12 b128 = 48 VGPR.
// Swizzle (BK=32): store-side k-chunk = (tid&3)^(row&3) at linear pos tid&3;
// read pos = quad^(l16&3). Same involution both sides; 0 bank conflicts.
// Ledger: tile kt's buf-reads all issue pre-barrier(kt) and are consumed
// (lgkm-drained) by O3/O4; next staging into buf issues >= 1 barrier + 1
// octet + HBM-latency later -> no WAR window. nb-prefetch reads only after
// the vmcnt(0)+barrier proving nb staged chip-wide; sched_barrier(0) pins.
__global__ __launch_bounds__(512, 4) void gemm_kernel(const unsigned short* __restrict__ A,
                                                      const unsigned short* __restrict__ W,
                                                      unsigned short* __restrict__ u,
                                                      unsigned short* __restrict__ f,
                                                      unsigned short* __restrict__ r) {
    __shared__ __align__(16) unsigned short ldsA[2 * BM * BK];   // 2 x 16 KiB
    __shared__ __align__(16) unsigned short ldsB[2 * BM * BK];   // 2 x 16 KiB

    const int tid  = threadIdx.x;          // 0..511
    const int wave = tid >> 6;             // 0..7
    const int lane = tid & 63;
    const int quad = lane >> 4;
    const int l16  = lane & 15;
    const int wr   = wave >> 2;            // 0..1
    const int wc   = wave & 3;             // 0..3

    // T1: bijective XCD swizzle (NWG=768, 768%8==0)
    const int orig = blockIdx.y * GX + blockIdx.x;
    const int swz  = (orig & 7) * (NWG / 8) + (orig >> 3);
    const int tx   = swz % GX;
    const int ty   = swz / GX;
    const int m0   = ty * BM;
    const int n0   = tx * BN;

    // staging: thread -> (row tid>>2 within 128-row block, chunk tid&3)
    const int rS = tid >> 2;                          // 0..127
    const int kS = ((tid & 3) ^ (rS & 3)) * 8;        // pre-swizzled global k-chunk
    const unsigned short* gA = A + (size_t)(m0 + rS) * K_DIM + kS;
    const unsigned short* gB = W + (size_t)(n0 + rS) * K_DIM + kS;

    // fragment-read constants: row*32 shorts + swizzled chunk pos
    const int cpos8 = (quad ^ (l16 & 3)) * 8;
    const int aBase = wr * 2048 + l16 * 32 + cpos8;   // wr*64 rows * 32
    const int bBase = wc * 1024 + l16 * 32 + cpos8;   // wc*32 rows * 32

    floatx4 acc[2][2][4][2] = {};
    short8 aP[4], aQ[4], b0[2], b1[2];   // 12 b128 = 48 VGPR

#define STAGE_A(BO_, KT_) do { \
    async16(gA + (size_t)(KT_) * 32, &ldsA[(BO_) + (size_t)tid * 8]); \
    async16(gA + (size_t)128 * K_DIM + (size_t)(KT_) * 32, \
            &ldsA[(BO_) + 4096 + (size_t)tid * 8]); \
} while (0)

#define STAGE_B(BO_, KT_) do { \
    async16(gB + (size_t)(KT_) * 32, &ldsB[(BO_) + (size_t)tid * 8]); \
    async16(gB + (size_t)128 * K_DIM + (size_t)(KT_) * 32, \
            &ldsB[(BO_) + 4096 + (size_t)tid * 8]); \
} while (0)

// read one A-half (4 M-frags = 4 ds_read_b128); rows MH*128 + wr*64 + i*16 + l16
#define RD_A4(ARR_, BO_, MH_) do { \
    const unsigned short* pa_ = &ldsA[(BO_) + (MH_) * 4096 + aBase]; \
    ARR_[0] = *(const short8*)(pa_); \
    ARR_[1] = *(const short8*)(pa_ + 512); \
    ARR_[2] = *(const short8*)(pa_ + 1024); \
    ARR_[3] = *(const short8*)(pa_ + 1536); \
} while (0)

// read one B-half (2 N-frags = 2 ds_read_b128); rows NH*128 + wc*32 + j*16 + l16
#define RD_B2(ARR_, BO_, NH_) do { \
    const unsigned short* pb_ = &ldsB[(BO_) + (NH_) * 4096 + bBase]; \
    ARR_[0] = *(const short8*)(pb_); \
    ARR_[1] = *(const short8*)(pb_ + 512); \
} while (0)

// 8 MFMA on fully-resident operands: A-half ARR_ x B-half BRR_
#define OCT(ARR_, BRR_, MH_, NH_) do { \
    __builtin_amdgcn_s_setprio(1); \
    _Pragma("unroll") \
    for (int i_ = 0; i_ < 4; i_++) { \
        _Pragma("unroll") \
        for (int j_ = 0; j_ < 2; j_++) { \
            acc[MH_][NH_][i_][j_] = __builtin_amdgcn_mfma_f32_16x16x32_bf16( \
                ARR_[i_], BRR_[j_], acc[MH_][NH_][i_][j_], 0, 0, 0); \
        } \
    } \
    __builtin_amdgcn_s_setprio(0); \
} while (0)

#define TILE_BARRIER do { \
    asm volatile("s_waitcnt vmcnt(0)" ::: "memory"); \
    __builtin_amdgcn_s_barrier(); \
    __builtin_amdgcn_sched_barrier(0); \
} while (0)

    // prologue: stage tile 0 into buf 0; sync; preload A-h0 and B-h0
    STAGE_A(0, 0); STAGE_B(0, 0);
    TILE_BARRIER;
    RD_A4(aP, 0, 0);
    RD_B2(b0, 0, 0);

    // main loop: tiles 0..30; tile kt computes from bufS, stages kt+1 into nbS
    for (int kt = 0; kt < NT - 1; ++kt) {
        const int bufS = (kt & 1) << 13;          // *8192 shorts
        const int nbS  = bufS ^ 8192;
        STAGE_A(nbS, kt + 1); STAGE_B(nbS, kt + 1);   // 4 VMEM, oldest at barrier
        RD_B2(b1, bufS, 1);        // B-h1  -> used O2
        OCT(aP, b0, 0, 0);         // O1: A-h0 * B-h0
        RD_A4(aQ, bufS, 1);        // A-h1  -> used O3
        OCT(aP, b1, 0, 1);         // O2: A-h0 * B-h1   (aP dead)
        OCT(aQ, b0, 1, 0);         // O3: A-h1 * B-h0   (b0 dead)
        TILE_BARRIER;              // nb staged chip-wide; buf reads consumed
        RD_A4(aP, nbS, 0);         // A-h0' (next tile) -> next O1
        RD_B2(b0, nbS, 0);         // B-h0' (next tile) -> next O1
        OCT(aQ, b1, 1, 1);         // O4: A-h1 * B-h1
    }

    // tail tile 31 (buf 1): staged+synced by tile 30; no staging/prefetch
    {
        const int bufS = 8192;
        RD_B2(b1, bufS, 1);
        OCT(aP, b0, 0, 0);
        RD_A4(aQ, bufS, 1);
        OCT(aP, b1, 0, 1);
        OCT(aQ, b0, 1, 0);
        OCT(aQ, b1, 1, 1);
    }

#undef TILE_BARRIER
#undef OCT
#undef RD_B2
#undef RD_A4
#undef STAGE_B
#undef STAGE_A

    // Epilogue: region uniform per block (BN=256 divides the 1024 gate span)
    const int region = n0 >> 10;          // 0 -> u, 1 -> f, 2 -> r
    const int nnb = n0 & 1023;
    unsigned short* dst = (region == 0) ? u : ((region == 1) ? f : r);
    const bool sig = (region != 0);
    #pragma unroll
    for (int mh = 0; mh < 2; mh++) {
        #pragma unroll
        for (int nh = 0; nh < 2; nh++) {
            #pragma unroll
            for (int i = 0; i < 4; i++) {
                #pragma unroll
                for (int j = 0; j < 2; j++) {
                    #pragma unroll
                    for (int t = 0; t < 4; t++) {
                        const int gm = m0 + mh * 128 + wr * 64 + i * 16 + quad * 4 + t;
                        const int nn = nnb + nh * 128 + wc * 32 + j * 16 + l16;
                        float v = acc[mh][nh][i][j][t];
                        if (sig) v = sigmoidf_fast(v);
                        dst[(size_t)gm * D_DIM + nn] = f32_to_bf16(v);
                    }
                }
            }
        }
    }
}

// ---------------- Scan phase 1: per-chunk affine reduce (4 channels/thread) --
__global__ __launch_bounds__(256) void scan_reduce(const unsigned short* __restrict__ f,
                                                   const unsigned short* __restrict__ u,
                                                   float* __restrict__ Ac,
                                                   float* __restrict__ bc) {
    const int ch4   = (blockIdx.x * 256 + threadIdx.x) * 4;
    const int chunk = blockIdx.y;
    const size_t base = (size_t)chunk * CL * CH + ch4;
    float A0 = 1.0f, A1 = 1.0f, A2 = 1.0f, A3 = 1.0f;
    float b0 = 0.0f, b1 = 0.0f, b2 = 0.0f, b3 = 0.0f;
    #pragma unroll
    for (int i = 0; i < CL; i++) {
        const size_t idx = base + (size_t)i * CH;
        const uint2 fp = *(const uint2*)(f + idx);
        const uint2 up = *(const uint2*)(u + idx);
        const float f0 = bf16_lo(fp.x), f1 = bf16_hi(fp.x);
        const float f2 = bf16_lo(fp.y), f3 = bf16_hi(fp.y);
        const float u0 = bf16_lo(up.x), u1 = bf16_hi(up.x);
        const float u2 = bf16_lo(up.y), u3 = bf16_hi(up.y);
        b0 = f0 * (b0 - u0) + u0;   // f*b + (1-f)*u
        b1 = f1 * (b1 - u1) + u1;
        b2 = f2 * (b2 - u2) + u2;
        b3 = f3 * (b3 - u3) + u3;
        A0 *= f0; A1 *= f1; A2 *= f2; A3 *= f3;
    }
    *(float4*)(Ac + chunk * CH + ch4) = make_float4(A0, A1, A2, A3);
    *(float4*)(bc + chunk * CH + ch4) = make_float4(b0, b1, b2, b3);
}

// ---------------- Scan phase 2: spine (exclusive scan over chunks) -----------
__global__ __launch_bounds__(256) void scan_spine(const float* __restrict__ Ac,
                                                  const float* __restrict__ bc,
                                                  const float* __restrict__ c0,
                                                  float* __restrict__ cst) {
    const int ch = blockIdx.x * 256 + threadIdx.x;
    float c = c0[ch];
    #pragma unroll 16
    for (int j = 0; j < NC; j++) {
        cst[j * CH + ch] = c;
        c = Ac[j * CH + ch] * c + bc[j * CH + ch];
    }
}

// ---------------- Scan phase 3: apply + fused output (4 channels/thread) -----
__global__ __launch_bounds__(256) void scan_apply(const unsigned short* __restrict__ f,
                                                  const unsigned short* __restrict__ u,
                                                  const unsigned short* __restrict__ r,
                                                  const float* __restrict__ x,
                                                  const float* __restrict__ meanIn,
                                                  const float* __restrict__ rstdIn,
                                                  const float* __restrict__ gamma,
                                                  const float* __restrict__ beta,
                                                  const float* __restrict__ cst,
                                                  float* __restrict__ out,
                                                  float* __restrict__ lastc) {
    const int ch4   = (blockIdx.x * 256 + threadIdx.x) * 4;
    const int chunk = blockIdx.y;
    const int bidx  = ch4 >> 10;       // batch index (uniform per block)
    const int d     = ch4 & 1023;
    const float4 g  = *(const float4*)(gamma + d);
    const float4 be = *(const float4*)(beta + d);
    const size_t base = (size_t)chunk * CL * CH + ch4;
    float4 cc = *(const float4*)(cst + chunk * CH + ch4);
    float c0v = cc.x, c1v = cc.y, c2v = cc.z, c3v = cc.w;
    #pragma unroll 4
    for (int i = 0; i < CL; i++) {
        const int rowLB = (chunk * CL + i) * B_DIM + bidx;   // uniform
        const float mu = meanIn[rowLB];
        const float rs = rstdIn[rowLB];
        const size_t idx = base + (size_t)i * CH;
        const uint2 fp = *(const uint2*)(f + idx);
        const uint2 up = *(const uint2*)(u + idx);
        const uint2 rp = *(const uint2*)(r + idx);
        const float4 xv = *(const float4*)(x + idx);
        const float f0 = bf16_lo(fp.x), f1 = bf16_hi(fp.x);
        const float f2 = bf16_lo(fp.y), f3 = bf16_hi(fp.y);
        const float u0 = bf16_lo(up.x), u1 = bf16_hi(up.x);
        const float u2 = bf16_lo(up.y), u3 = bf16_hi(up.y);
        c0v = f0 * (c0v - u0) + u0;
        c1v = f1 * (c1v - u1) + u1;
        c2v = f2 * (c2v - u2) + u2;
        c3v = f3 * (c3v - u3) + u3;
        const float r0 = bf16_lo(rp.x), r1 = bf16_hi(rp.x);
        const float r2 = bf16_lo(rp.y), r3 = bf16_hi(rp.y);
        const float n0 = (xv.x - mu) * rs * g.x + be.x;
        const float n1 = (xv.y - mu) * rs * g.y + be.y;
        const float n2 = (xv.z - mu) * rs * g.z + be.z;
        const float n3 = (xv.w - mu) * rs * g.w + be.w;
        float4 o;
        o.x = xv.x + r0 * tanhf_fast(c0v) + (1.0f - r0) * n0;
        o.y = xv.y + r1 * tanhf_fast(c1v) + (1.0f - r1) * n1;
        o.z = xv.z + r2 * tanhf_fast(c2v) + (1.0f - r2) * n2;
        o.w = xv.w + r3 * tanhf_fast(c3v) + (1.0f - r3) * n3;
        *(float4*)(out + idx) = o;
    }
    if (chunk == NC - 1) *(float4*)(lastc + ch4) = make_float4(c0v, c1v, c2v, c3v);
}

extern "C" void kernel_launch(void* const* d_in, const int* in_sizes, int n_in,
                              void* d_out, int out_size, void* d_ws, size_t ws_size,
                              hipStream_t stream) {
    const float* x     = (const float*)d_in[0];   // (L,B,D)
    const float* c0    = (const float*)d_in[1];   // (B,D)
    const float* W     = (const float*)d_in[2];   // (3D,D)
    const float* gamma = (const float*)d_in[3];   // (D,)
    const float* beta  = (const float*)d_in[4];   // (D,)

    float* out   = (float*)d_out;                       // (L,B,D)
    float* lastc = out + (size_t)M_DIM * D_DIM;         // (B,D)

    char* ws = (char*)d_ws;
    unsigned short* xn = (unsigned short*)ws;  ws += (size_t)M_DIM * K_DIM * 2;  // 33.5 MB
    unsigned short* Wb = (unsigned short*)ws;  ws += (size_t)N_DIM * K_DIM * 2;  // 6.3 MB
    unsigned short* u  = (unsigned short*)ws;  ws += (size_t)M_DIM * D_DIM * 2;  // 33.5 MB
    unsigned short* f  = (unsigned short*)ws;  ws += (size_t)M_DIM * D_DIM * 2;  // 33.5 MB
    unsigned short* r  = (unsigned short*)ws;  ws += (size_t)M_DIM * D_DIM * 2;  // 33.5 MB
    float* meanBuf = (float*)ws;               ws += (size_t)M_DIM * 4;
    float* rstdBuf = (float*)ws;               ws += (size_t)M_DIM * 4;
    float* Ac  = (float*)ws;                   ws += (size_t)NC * CH * 4;
    float* bc  = (float*)ws;                   ws += (size_t)NC * CH * 4;
    float* cst = (float*)ws;                   ws += (size_t)NC * CH * 4;

    ln_kernel<<<M_DIM / 4, 256, 0, stream>>>(x, gamma, beta, xn, meanBuf, rstdBuf);
    wconv_kernel<<<(N_DIM * K_DIM) / 1024, 256, 0, stream>>>(W, Wb);
    gemm_kernel<<<dim3(GX, GY), 512, 0, stream>>>(xn, Wb, u, f, r);
    scan_reduce<<<dim3(CH / 1024, NC), 256, 0, stream>>>(f, u, Ac, bc);
    scan_spine<<<CH / 256, 256, 0, stream>>>(Ac, bc, c0, cst);
    scan_apply<<<dim3(CH / 1024, NC), 256, 0, stream>>>(f, u, r, x, meanBuf, rstdBuf,
                                                        gamma, beta, cst, out, lastc);
}

// Round 7
// 292.092 us; speedup vs baseline: 4.1112x; 4.1112x over previous
//
#include <hip/hip_runtime.h>
#include <hip/hip_bf16.h>
#include <stdint.h>

#define L_DIM 2048
#define B_DIM 8
#define D_DIM 1024
#define M_DIM (L_DIM * B_DIM)   // 16384 rows
#define N_DIM (3 * D_DIM)       // 3072
#define K_DIM D_DIM             // 1024
#define CH    (B_DIM * D_DIM)   // 8192 scan channels
#define EPSLN 1e-5f
#define NC 128                  // scan chunks
#define CL (L_DIM / NC)         // 16 steps per chunk

// ---- GEMM geometry: 256^2 tile, BK=64, m201-style deep-pipelined 8-phase ----
#define BM 256
#define BN 256
#define BK 64
#define NT (K_DIM / BK)         // 16 K-tiles -> 8 iterations of 2 tiles
#define GX (N_DIM / BN)         // 12
#define GY (M_DIM / BM)         // 64
#define NWG (GX * GY)           // 768 (divisible by 8 -> bijective XCD swizzle)

typedef __attribute__((ext_vector_type(8))) short short8;
typedef __attribute__((ext_vector_type(4))) float floatx4;

static __device__ __forceinline__ float bf16_lo(unsigned int p) {
    union { unsigned int u; float f; } v; v.u = p << 16; return v.f;
}
static __device__ __forceinline__ float bf16_hi(unsigned int p) {
    union { unsigned int u; float f; } v; v.u = p & 0xffff0000u; return v.f;
}
static __device__ __forceinline__ unsigned short f32_to_bf16(float f) {
    union { float f; unsigned int u; } v;
    v.f = f;
    unsigned int u = v.u;
    u += 0x7fffu + ((u >> 16) & 1u);   // round-to-nearest-even
    return (unsigned short)(u >> 16);
}
static __device__ __forceinline__ float sigmoidf_fast(float v) {
    return 1.0f / (1.0f + __expf(-v));
}
static __device__ __forceinline__ float tanhf_fast(float c) {
    return 1.0f - 2.0f / (1.0f + __expf(2.0f * c));
}

// async global -> LDS, 16B per lane (global_load_lds_dwordx4)
static __device__ __forceinline__ void async16(const void* g, void* l) {
    __builtin_amdgcn_global_load_lds(
        (const __attribute__((address_space(1))) unsigned int*)g,
        (__attribute__((address_space(3))) unsigned int*)l,
        16, 0, 0);
}

// ---------------- LayerNorm: x[M,D] fp32 -> x_norm bf16 [M,D] + mean/rstd ----
// wave-per-row (4 rows/block). No LDS, no __syncthreads. (r5, verified)
__global__ __launch_bounds__(256) void ln_kernel(const float* __restrict__ x,
                                                 const float* __restrict__ gamma,
                                                 const float* __restrict__ beta,
                                                 unsigned short* __restrict__ xn,
                                                 float* __restrict__ meanOut,
                                                 float* __restrict__ rstdOut) {
    const int wid  = threadIdx.x >> 6;          // wave 0..3
    const int lane = threadIdx.x & 63;
    const int row  = blockIdx.x * 4 + wid;
    const float* xr = x + (size_t)row * D_DIM;
    float4 v[4];
    float s = 0.0f, s2 = 0.0f;
    #pragma unroll
    for (int j = 0; j < 4; j++) {
        v[j] = *(const float4*)(xr + j * 256 + lane * 4);
        s  += v[j].x + v[j].y + v[j].z + v[j].w;
        s2 += v[j].x * v[j].x + v[j].y * v[j].y + v[j].z * v[j].z + v[j].w * v[j].w;
    }
    #pragma unroll
    for (int o = 32; o > 0; o >>= 1) {
        s  += __shfl_xor(s, o, 64);
        s2 += __shfl_xor(s2, o, 64);
    }
    const float mean = s * (1.0f / D_DIM);
    const float var  = s2 * (1.0f / D_DIM) - mean * mean;
    const float rstd = rsqrtf(var + EPSLN);
    if (lane == 0) { meanOut[row] = mean; rstdOut[row] = rstd; }
    #pragma unroll
    for (int j = 0; j < 4; j++) {
        const int col = j * 256 + lane * 4;
        const float4 g = *(const float4*)(gamma + col);
        const float4 b = *(const float4*)(beta + col);
        unsigned short o0 = f32_to_bf16((v[j].x - mean) * rstd * g.x + b.x);
        unsigned short o1 = f32_to_bf16((v[j].y - mean) * rstd * g.y + b.y);
        unsigned short o2 = f32_to_bf16((v[j].z - mean) * rstd * g.z + b.z);
        unsigned short o3 = f32_to_bf16((v[j].w - mean) * rstd * g.w + b.w);
        uint2 packed;
        packed.x = (unsigned int)o0 | ((unsigned int)o1 << 16);
        packed.y = (unsigned int)o2 | ((unsigned int)o3 << 16);
        *(uint2*)(xn + (size_t)row * D_DIM + col) = packed;
    }
}

// ---------------- W fp32 [3D, D] -> bf16 ----------------
__global__ __launch_bounds__(256) void wconv_kernel(const float* __restrict__ W,
                                                    unsigned short* __restrict__ Wb) {
    const size_t i = ((size_t)blockIdx.x * 256 + threadIdx.x) * 4;
    float4 v = *(const float4*)(W + i);
    uint2 packed;
    packed.x = (unsigned int)f32_to_bf16(v.x) | ((unsigned int)f32_to_bf16(v.y) << 16);
    packed.y = (unsigned int)f32_to_bf16(v.z) | ((unsigned int)f32_to_bf16(v.w) << 16);
    *(uint2*)(Wb + i) = packed;
}

// ---------------- GEMM: ufr[m,e] = sum_k xn[m,k] * W[e,k]  (NT, bf16 MFMA) ---
// ROUND-7: r1's verified 8-phase skeleton (2 barriers/phase, lgkmcnt(0)
// before MFMA, interleaved quadrant ownership, XOR chunk swizzle, 128KB LDS)
// with the ONE change m218 isolated at +38-73%: DEEP counted-vmcnt pipeline.
//   - Fixed buffer roles: buf0 = even K-tiles, buf1 = odd K-tiles.
//   - Iteration i computes tiles 2i (phases 1-4) and 2i+1 (phases 5-8),
//     stages ONE half-tile per phase, vmcnt(6) ONLY at phases 4 and 8.
//   - Stage order: p1:(2i+1,A1)>b1  p2:(2i+2,A0)>b0  p3:(2i+2,B0)>b0
//     p4:(2i+2,B1)>b0  p5:(2i+2,A1)>b0  p6:(2i+3,A0)>b1  p7:(2i+3,B0)>b1
//     p8:(2i+3,B1)>b1.  Every half: >=3 phases issue->forced-retire; lands
//     chip-wide (vmcnt + barrier) 1-4 phases before first read.
//   - WAR: each stage into region R issues >=1 phase after R's last read
//     (reads are lgkm-drained pre-MFMA, then end-of-phase barrier).
//   - Queue sim: outstanding peaks at 14 loads at p4/p8; vmcnt(6) retires
//     exactly the 4 halves consumed next; steady state 3 halves in flight.
// Reads: p1/p5: A-half0 (8x b128) + B-half0 (4x); p2/p6: B-half1 (4x);
// p3/p7: A-half1 (8x); p4/p8: none (registers b[2][..] hold both B halves).
__global__ __launch_bounds__(512, 2) void gemm_kernel(const unsigned short* __restrict__ A,
                                                      const unsigned short* __restrict__ W,
                                                      unsigned short* __restrict__ u,
                                                      unsigned short* __restrict__ f,
                                                      unsigned short* __restrict__ r) {
    __shared__ __align__(16) unsigned short ldsA[2][BM * BK];   // 2 x 32 KiB
    __shared__ __align__(16) unsigned short ldsB[2][BM * BK];   // 2 x 32 KiB

    const int tid  = threadIdx.x;          // 0..511
    const int wave = tid >> 6;             // 0..7
    const int lane = tid & 63;
    const int quad = lane >> 4;
    const int l16  = lane & 15;
    const int wr   = wave >> 2;            // 0..1
    const int wc   = wave & 3;             // 0..3

    // T1: bijective XCD swizzle (NWG=768, 768%8==0)
    const int orig = blockIdx.y * GX + blockIdx.x;
    const int swz  = (orig & 7) * (NWG / 8) + (orig >> 3);
    const int tx   = swz % GX;
    const int ty   = swz / GX;
    const int m0   = ty * BM;
    const int n0   = tx * BN;

    // staging: thread -> (row tid>>3 within 64-row group, chunk tid&7)
    const int rS = tid >> 3;                          // 0..63
    const int kS = ((tid & 7) ^ (rS & 7)) * 8;        // pre-swizzled global k-chunk
    const unsigned short* gA = A + (size_t)(m0 + rS) * K_DIM + kS;
    const unsigned short* gB = W + (size_t)(n0 + rS) * K_DIM + kS;

    // fragment-read constants
    const int px     = l16 & 7;
    const int p0_8   = (quad ^ px) * 8;
    const int p1_8   = ((quad + 4) ^ px) * 8;
    const int l16_64 = l16 * 64;
    const int wr4096 = wr * 4096;
    const int wc2048 = wc * 2048;

    floatx4 acc[2][2][4][2] = {};
    short8 a[4][2];        // current A half: 4 M-frags x 2 k-substeps
    short8 b[2][2][2];     // [nh][j][s]: both B halves live across a tile

#define STAGE_A(BUF_, KT_, H_) do { \
    async16(gA + (size_t)((H_) * 128) * K_DIM + (size_t)(KT_) * 64, \
            &ldsA[BUF_][(H_) * 8192 + (size_t)tid * 8]); \
    async16(gA + (size_t)((H_) * 128 + 64) * K_DIM + (size_t)(KT_) * 64, \
            &ldsA[BUF_][(H_) * 8192 + 4096 + (size_t)tid * 8]); \
} while (0)

#define STAGE_B(BUF_, KT_, H_) do { \
    async16(gB + (size_t)((H_) * 128) * K_DIM + (size_t)(KT_) * 64, \
            &ldsB[BUF_][(H_) * 8192 + (size_t)tid * 8]); \
    async16(gB + (size_t)((H_) * 128 + 64) * K_DIM + (size_t)(KT_) * 64, \
            &ldsB[BUF_][(H_) * 8192 + 4096 + (size_t)tid * 8]); \
} while (0)

#define RD_A(BUF_, MH_) do { \
    const unsigned short* pa_ = &ldsA[BUF_][(MH_) * 8192 + wr4096 + l16_64]; \
    _Pragma("unroll") \
    for (int i_ = 0; i_ < 4; i_++) { \
        a[i_][0] = *(const short8*)(pa_ + i_ * 1024 + p0_8); \
        a[i_][1] = *(const short8*)(pa_ + i_ * 1024 + p1_8); \
    } \
} while (0)

#define RD_B(BUF_, NH_) do { \
    const unsigned short* pb_ = &ldsB[BUF_][(NH_) * 8192 + wc2048 + l16_64]; \
    _Pragma("unroll") \
    for (int j_ = 0; j_ < 2; j_++) { \
        b[NH_][j_][0] = *(const short8*)(pb_ + j_ * 1024 + p0_8); \
        b[NH_][j_][1] = *(const short8*)(pb_ + j_ * 1024 + p1_8); \
    } \
} while (0)

// barrier + compiler memory fence (builtin s_barrier is not an IR fence)
#define BAR do { \
    __builtin_amdgcn_s_barrier(); \
    asm volatile("" ::: "memory"); \
    __builtin_amdgcn_sched_barrier(0); \
} while (0)
#define LGKM0 do { asm volatile("s_waitcnt lgkmcnt(0)" ::: "memory"); \
                   __builtin_amdgcn_sched_barrier(0); } while (0)
#define VMW6 asm volatile("s_waitcnt vmcnt(6)" ::: "memory")
#define VMW0 asm volatile("s_waitcnt vmcnt(0)" ::: "memory")

#define MFMA_Q(MH_, NH_) do { \
    __builtin_amdgcn_s_setprio(1); \
    _Pragma("unroll") \
    for (int i_ = 0; i_ < 4; i_++) { \
        _Pragma("unroll") \
        for (int j_ = 0; j_ < 2; j_++) { \
            acc[MH_][NH_][i_][j_] = __builtin_amdgcn_mfma_f32_16x16x32_bf16( \
                a[i_][0], b[NH_][j_][0], acc[MH_][NH_][i_][j_], 0, 0, 0); \
            acc[MH_][NH_][i_][j_] = __builtin_amdgcn_mfma_f32_16x16x32_bf16( \
                a[i_][1], b[NH_][j_][1], acc[MH_][NH_][i_][j_], 0, 0, 0); \
        } \
    } \
    __builtin_amdgcn_s_setprio(0); \
} while (0)

    // prologue: tile0 (4 halves) + tile1 {A0,B0,B1}; vmcnt(6) retires tile0
    STAGE_A(0, 0, 0); STAGE_B(0, 0, 0); STAGE_B(0, 0, 1); STAGE_A(0, 0, 1);
    STAGE_A(1, 1, 0); STAGE_B(1, 1, 0); STAGE_B(1, 1, 1);
    VMW6;
    BAR;

    // main loop: iterations i = 0..6 (tiles 0..13), staging tiles up to 15
    for (int i = 0; i < 7; ++i) {
        const int t = 2 * i;
        // p1: tile t Q00
        RD_A(0, 0); RD_B(0, 0);
        STAGE_A(1, t + 1, 1);
        BAR; LGKM0; MFMA_Q(0, 0); BAR;
        // p2: tile t Q01
        RD_B(0, 1);
        STAGE_A(0, t + 2, 0);
        BAR; LGKM0; MFMA_Q(0, 1); BAR;
        // p3: tile t Q11
        RD_A(0, 1);
        STAGE_B(0, t + 2, 0);
        BAR; LGKM0; MFMA_Q(1, 1); BAR;
        // p4: tile t Q10 (regs only); counted wait
        STAGE_B(0, t + 2, 1);
        BAR; MFMA_Q(1, 0); VMW6; BAR;
        // p5: tile t+1 Q00
        RD_A(1, 0); RD_B(1, 0);
        STAGE_A(0, t + 2, 1);
        BAR; LGKM0; MFMA_Q(0, 0); BAR;
        // p6: tile t+1 Q01
        RD_B(1, 1);
        STAGE_A(1, t + 3, 0);
        BAR; LGKM0; MFMA_Q(0, 1); BAR;
        // p7: tile t+1 Q11
        RD_A(1, 1);
        STAGE_B(1, t + 3, 0);
        BAR; LGKM0; MFMA_Q(1, 1); BAR;
        // p8: tile t+1 Q10; counted wait
        STAGE_B(1, t + 3, 1);
        BAR; MFMA_Q(1, 0); VMW6; BAR;
    }

    // tail: tiles 14 (buf0, fully landed by iter-6 p8 wait) and 15 (buf1)
    {
        STAGE_A(1, 15, 1);           // last half of tile 15
        RD_A(0, 0); RD_B(0, 0);
        LGKM0; MFMA_Q(0, 0);
        RD_B(0, 1);
        LGKM0; MFMA_Q(0, 1);
        RD_A(0, 1);
        LGKM0; MFMA_Q(1, 1);
        MFMA_Q(1, 0);
        VMW0; BAR;                   // tile 15 landed chip-wide
        RD_A(1, 0); RD_B(1, 0);
        LGKM0; MFMA_Q(0, 0);
        RD_B(1, 1);
        LGKM0; MFMA_Q(0, 1);
        RD_A(1, 1);
        LGKM0; MFMA_Q(1, 1);
        MFMA_Q(1, 0);
    }

#undef MFMA_Q
#undef VMW0
#undef VMW6
#undef LGKM0
#undef BAR
#undef RD_B
#undef RD_A
#undef STAGE_B
#undef STAGE_A

    // Epilogue: region uniform per block (BN=256 divides the 1024 gate span)
    const int region = n0 >> 10;          // 0 -> u, 1 -> f, 2 -> r
    const int nnb = n0 & 1023;
    unsigned short* dst = (region == 0) ? u : ((region == 1) ? f : r);
    const bool sig = (region != 0);
    #pragma unroll
    for (int mh = 0; mh < 2; mh++) {
        #pragma unroll
        for (int nh = 0; nh < 2; nh++) {
            #pragma unroll
            for (int i = 0; i < 4; i++) {
                #pragma unroll
                for (int j = 0; j < 2; j++) {
                    #pragma unroll
                    for (int t = 0; t < 4; t++) {
                        const int gm = m0 + mh * 128 + wr * 64 + i * 16 + quad * 4 + t;
                        const int nn = nnb + nh * 128 + wc * 32 + j * 16 + l16;
                        float v = acc[mh][nh][i][j][t];
                        if (sig) v = sigmoidf_fast(v);
                        dst[(size_t)gm * D_DIM + nn] = f32_to_bf16(v);
                    }
                }
            }
        }
    }
}

// ---------------- Scan phase 1: per-chunk affine reduce (4 channels/thread) --
__global__ __launch_bounds__(256) void scan_reduce(const unsigned short* __restrict__ f,
                                                   const unsigned short* __restrict__ u,
                                                   float* __restrict__ Ac,
                                                   float* __restrict__ bc) {
    const int ch4   = (blockIdx.x * 256 + threadIdx.x) * 4;
    const int chunk = blockIdx.y;
    const size_t base = (size_t)chunk * CL * CH + ch4;
    float A0 = 1.0f, A1 = 1.0f, A2 = 1.0f, A3 = 1.0f;
    float b0 = 0.0f, b1 = 0.0f, b2 = 0.0f, b3 = 0.0f;
    #pragma unroll
    for (int i = 0; i < CL; i++) {
        const size_t idx = base + (size_t)i * CH;
        const uint2 fp = *(const uint2*)(f + idx);
        const uint2 up = *(const uint2*)(u + idx);
        const float f0 = bf16_lo(fp.x), f1 = bf16_hi(fp.x);
        const float f2 = bf16_lo(fp.y), f3 = bf16_hi(fp.y);
        const float u0 = bf16_lo(up.x), u1 = bf16_hi(up.x);
        const float u2 = bf16_lo(up.y), u3 = bf16_hi(up.y);
        b0 = f0 * (b0 - u0) + u0;   // f*b + (1-f)*u
        b1 = f1 * (b1 - u1) + u1;
        b2 = f2 * (b2 - u2) + u2;
        b3 = f3 * (b3 - u3) + u3;
        A0 *= f0; A1 *= f1; A2 *= f2; A3 *= f3;
    }
    *(float4*)(Ac + chunk * CH + ch4) = make_float4(A0, A1, A2, A3);
    *(float4*)(bc + chunk * CH + ch4) = make_float4(b0, b1, b2, b3);
}

// ---------------- Scan phase 2: spine (exclusive scan over chunks) -----------
__global__ __launch_bounds__(256) void scan_spine(const float* __restrict__ Ac,
                                                  const float* __restrict__ bc,
                                                  const float* __restrict__ c0,
                                                  float* __restrict__ cst) {
    const int ch = blockIdx.x * 256 + threadIdx.x;
    float c = c0[ch];
    #pragma unroll 16
    for (int j = 0; j < NC; j++) {
        cst[j * CH + ch] = c;
        c = Ac[j * CH + ch] * c + bc[j * CH + ch];
    }
}

// ---------------- Scan phase 3: apply + fused output (4 channels/thread) -----
__global__ __launch_bounds__(256) void scan_apply(const unsigned short* __restrict__ f,
                                                  const unsigned short* __restrict__ u,
                                                  const unsigned short* __restrict__ r,
                                                  const float* __restrict__ x,
                                                  const float* __restrict__ meanIn,
                                                  const float* __restrict__ rstdIn,
                                                  const float* __restrict__ gamma,
                                                  const float* __restrict__ beta,
                                                  const float* __restrict__ cst,
                                                  float* __restrict__ out,
                                                  float* __restrict__ lastc) {
    const int ch4   = (blockIdx.x * 256 + threadIdx.x) * 4;
    const int chunk = blockIdx.y;
    const int bidx  = ch4 >> 10;       // batch index (uniform per block)
    const int d     = ch4 & 1023;
    const float4 g  = *(const float4*)(gamma + d);
    const float4 be = *(const float4*)(beta + d);
    const size_t base = (size_t)chunk * CL * CH + ch4;
    float4 cc = *(const float4*)(cst + chunk * CH + ch4);
    float c0v = cc.x, c1v = cc.y, c2v = cc.z, c3v = cc.w;
    #pragma unroll 4
    for (int i = 0; i < CL; i++) {
        const int rowLB = (chunk * CL + i) * B_DIM + bidx;   // uniform
        const float mu = meanIn[rowLB];
        const float rs = rstdIn[rowLB];
        const size_t idx = base + (size_t)i * CH;
        const uint2 fp = *(const uint2*)(f + idx);
        const uint2 up = *(const uint2*)(u + idx);
        const uint2 rp = *(const uint2*)(r + idx);
        const float4 xv = *(const float4*)(x + idx);
        const float f0 = bf16_lo(fp.x), f1 = bf16_hi(fp.x);
        const float f2 = bf16_lo(fp.y), f3 = bf16_hi(fp.y);
        const float u0 = bf16_lo(up.x), u1 = bf16_hi(up.x);
        const float u2 = bf16_lo(up.y), u3 = bf16_hi(up.y);
        c0v = f0 * (c0v - u0) + u0;
        c1v = f1 * (c1v - u1) + u1;
        c2v = f2 * (c2v - u2) + u2;
        c3v = f3 * (c3v - u3) + u3;
        const float r0 = bf16_lo(rp.x), r1 = bf16_hi(rp.x);
        const float r2 = bf16_lo(rp.y), r3 = bf16_hi(rp.y);
        const float n0 = (xv.x - mu) * rs * g.x + be.x;
        const float n1 = (xv.y - mu) * rs * g.y + be.y;
        const float n2 = (xv.z - mu) * rs * g.z + be.z;
        const float n3 = (xv.w - mu) * rs * g.w + be.w;
        float4 o;
        o.x = xv.x + r0 * tanhf_fast(c0v) + (1.0f - r0) * n0;
        o.y = xv.y + r1 * tanhf_fast(c1v) + (1.0f - r1) * n1;
        o.z = xv.z + r2 * tanhf_fast(c2v) + (1.0f - r2) * n2;
        o.w = xv.w + r3 * tanhf_fast(c3v) + (1.0f - r3) * n3;
        *(float4*)(out + idx) = o;
    }
    if (chunk == NC - 1) *(float4*)(lastc + ch4) = make_float4(c0v, c1v, c2v, c3v);
}

extern "C" void kernel_launch(void* const* d_in, const int* in_sizes, int n_in,
                              void* d_out, int out_size, void* d_ws, size_t ws_size,
                              hipStream_t stream) {
    const float* x     = (const float*)d_in[0];   // (L,B,D)
    const float* c0    = (const float*)d_in[1];   // (B,D)
    const float* W     = (const float*)d_in[2];   // (3D,D)
    const float* gamma = (const float*)d_in[3];   // (D,)
    const float* beta  = (const float*)d_in[4];   // (D,)

    float* out   = (float*)d_out;                       // (L,B,D)
    float* lastc = out + (size_t)M_DIM * D_DIM;         // (B,D)

    char* ws = (char*)d_ws;
    unsigned short* xn = (unsigned short*)ws;  ws += (size_t)M_DIM * K_DIM * 2;  // 33.5 MB
    unsigned short* Wb = (unsigned short*)ws;  ws += (size_t)N_DIM * K_DIM * 2;  // 6.3 MB
    unsigned short* u  = (unsigned short*)ws;  ws += (size_t)M_DIM * D_DIM * 2;  // 33.5 MB
    unsigned short* f  = (unsigned short*)ws;  ws += (size_t)M_DIM * D_DIM * 2;  // 33.5 MB
    unsigned short* r  = (unsigned short*)ws;  ws += (size_t)M_DIM * D_DIM * 2;  // 33.5 MB
    float* meanBuf = (float*)ws;               ws += (size_t)M_DIM * 4;
    float* rstdBuf = (float*)ws;               ws += (size_t)M_DIM * 4;
    float* Ac  = (float*)ws;                   ws += (size_t)NC * CH * 4;
    float* bc  = (float*)ws;                   ws += (size_t)NC * CH * 4;
    float* cst = (float*)ws;                   ws += (size_t)NC * CH * 4;

    ln_kernel<<<M_DIM / 4, 256, 0, stream>>>(x, gamma, beta, xn, meanBuf, rstdBuf);
    wconv_kernel<<<(N_DIM * K_DIM) / 1024, 256, 0, stream>>>(W, Wb);
    gemm_kernel<<<dim3(GX, GY), 512, 0, stream>>>(xn, Wb, u, f, r);
    scan_reduce<<<dim3(CH / 1024, NC), 256, 0, stream>>>(f, u, Ac, bc);
    scan_spine<<<CH / 256, 256, 0, stream>>>(Ac, bc, c0, cst);
    scan_apply<<<dim3(CH / 1024, NC), 256, 0, stream>>>(f, u, r, x, meanBuf, rstdBuf,
                                                        gamma, beta, cst, out, lastc);
}